// Round 3
// baseline (779.299 us; speedup 1.0000x reference)
//
#include <hip/hip_runtime.h>

#define BATCH   8192
#define FEAT    256
#define NCLASS  100000
#define EPS_C   1e-6f

#define NC_ELEMS (NCLASS * FEAT)          // 25,600,000
#define NVEC (NC_ELEMS / 4)               // 6,400,000 float4s
#define COPY_BLOCKS (NVEC / 256)          // 25,000

// Copy centers -> d_out shifted by +1 float (aligned float4 load, __shfl_up
// shift, aligned float4 store). Blocks 0..31 additionally build the per-class
// linked lists: next[b] = atomicExch(&head[target[b]], b). head was memset to
// 0xFF (-1). Lists are complete before scatter_kernel launches (stream order).
__global__ void copy_build_kernel(const float* __restrict__ centers,
                                  float* __restrict__ out /* d_out base */,
                                  const int* __restrict__ target,
                                  int* __restrict__ head,
                                  int* __restrict__ next) {
    int v = blockIdx.x * blockDim.x + threadIdx.x;   // [0, NVEC)
    const float4* cvec = (const float4*)centers;
    float4 cv = cvec[v];                             // centers[4v .. 4v+3]
    int lane = threadIdx.x & 63;
    float prev = __shfl_up(cv.w, 1);                 // c[4v-1] from lane-1
    if (lane == 0) {
        prev = (v > 0) ? centers[4 * v - 1] : 0.0f;
    }
    float4 ov;
    ov.x = prev; ov.y = cv.x; ov.z = cv.y; ov.w = cv.z;
    ((float4*)out)[v] = ov;
    if (v == 0) out[NC_ELEMS] = centers[NC_ELEMS - 1];  // tail element

    if (blockIdx.x < (BATCH / 256)) {
        int b = blockIdx.x * 256 + threadIdx.x;
        int t = target[b];
        next[b] = atomicExch(&head[t], b);
    }
}

// One block per sample; 256 threads = FEAT.
// Every block: loss partial for its sample. Head blocks additionally walk
// their class list and write the updated center row with a PLAIN store
// (no atomics on d_out). Last finished block reduces the loss.
__global__ void scatter_kernel(const float* __restrict__ features,
                               const int* __restrict__ target,
                               const float* __restrict__ centers,
                               const int* __restrict__ head,
                               const int* __restrict__ next,
                               float* __restrict__ partials,
                               int* __restrict__ ticket,
                               float* __restrict__ out /* d_out base */) {
    int b = blockIdx.x;
    int d = threadIdx.x;
    int t = target[b];
    float c = centers[t * FEAT + d];
    float f = features[b * FEAT + d];
    float diff = c - f;

    // ---- loss partial: block-reduce diff^2 -> partials[b] (plain store)
    float sq = diff * diff;
    #pragma unroll
    for (int off = 32; off > 0; off >>= 1) sq += __shfl_down(sq, off, 64);
    __shared__ float red[4];
    __shared__ int is_last;
    int wave = threadIdx.x >> 6;
    int lane = threadIdx.x & 63;
    if (lane == 0) red[wave] = sq;
    __syncthreads();
    if (threadIdx.x == 0) {
        partials[b] = red[0] + red[1] + red[2] + red[3];
    }

    // ---- center update: only the head block of each class writes the row
    if (head[t] == b) {
        float sumf = f;          // s = b contributes features[b]
        int n = 1;
        for (int s = next[b]; s != -1; s = next[s]) {
            sumf += features[s * FEAT + d];
            n++;
        }
        float nf = (float)n;
        out[1 + t * FEAT + d] = c - (nf * c - sumf) / (nf + EPS_C);
    }

    // ---- last-block-done loss reduction
    __threadfence();
    if (threadIdx.x == 0) {
        int old = atomicAdd(ticket, 1);
        is_last = (old == BATCH - 1);
    }
    __syncthreads();
    if (is_last) {
        __threadfence();  // acquire: make all partials[] visible
        float s = 0.0f;
        for (int i = threadIdx.x; i < BATCH; i += 256) s += partials[i];
        #pragma unroll
        for (int off = 32; off > 0; off >>= 1) s += __shfl_down(s, off, 64);
        if (lane == 0) red[wave] = s;
        __syncthreads();
        if (threadIdx.x == 0) {
            out[0] = (red[0] + red[1] + red[2] + red[3]) / (float)(BATCH * FEAT);
        }
    }
}

extern "C" void kernel_launch(void* const* d_in, const int* in_sizes, int n_in,
                              void* d_out, int out_size, void* d_ws, size_t ws_size,
                              hipStream_t stream) {
    const float* features = (const float*)d_in[0];
    const int*   target   = (const int*)d_in[1];
    const float* centers  = (const float*)d_in[2];
    float* out = (float*)d_out;

    // workspace layout
    int*   head     = (int*)d_ws;                                  // 100000 ints
    int*   next     = head + NCLASS;                               // 8192 ints
    float* partials = (float*)(next + BATCH);                      // 8192 floats
    int*   ticket   = (int*)(partials + BATCH);                    // 1 int

    hipMemsetAsync(head, 0xFF, NCLASS * sizeof(int), stream);      // head = -1
    hipMemsetAsync(ticket, 0, sizeof(int), stream);
    copy_build_kernel<<<COPY_BLOCKS, 256, 0, stream>>>(centers, out, target, head, next);
    scatter_kernel<<<BATCH, FEAT, 0, stream>>>(features, target, centers,
                                               head, next, partials, ticket, out);
}

// Round 4
// 206.653 us; speedup vs baseline: 3.7711x; 3.7711x over previous
//
#include <hip/hip_runtime.h>

#define BATCH   8192
#define FEAT    256
#define NCLASS  100000
#define EPS_C   1e-6f

#define NC_ELEMS (NCLASS * FEAT)          // 25,600,000
#define NVEC (NC_ELEMS / 4)               // 6,400,000 float4s
#define COPY_BLOCKS (NVEC / 256)          // 25,000

// Copy centers -> d_out shifted by +1 float (aligned float4 load, __shfl_up
// shift, aligned float4 store). Blocks 0..31 additionally build the per-class
// linked lists: next[b] = atomicExch(&head[target[b]], b). head was memset to
// 0xFF (-1). Lists are complete before scatter_kernel launches (stream order).
__global__ void copy_build_kernel(const float* __restrict__ centers,
                                  float* __restrict__ out /* d_out base */,
                                  const int* __restrict__ target,
                                  int* __restrict__ head,
                                  int* __restrict__ next) {
    int v = blockIdx.x * blockDim.x + threadIdx.x;   // [0, NVEC)
    const float4* cvec = (const float4*)centers;
    float4 cv = cvec[v];                             // centers[4v .. 4v+3]
    int lane = threadIdx.x & 63;
    float prev = __shfl_up(cv.w, 1);                 // c[4v-1] from lane-1
    if (lane == 0) {
        prev = (v > 0) ? centers[4 * v - 1] : 0.0f;
    }
    float4 ov;
    ov.x = prev; ov.y = cv.x; ov.z = cv.y; ov.w = cv.z;
    ((float4*)out)[v] = ov;
    if (v == 0) out[NC_ELEMS] = centers[NC_ELEMS - 1];  // tail element

    if (blockIdx.x < (BATCH / 256)) {
        int b = blockIdx.x * 256 + threadIdx.x;
        int t = target[b];
        next[b] = atomicExch(&head[t], b);
    }
}

// One block per sample; 256 threads = FEAT. Plain stores only — no atomics,
// no fences (the R3 ticket+threadfence pattern cost 600us of serialization).
__global__ void scatter_kernel(const float* __restrict__ features,
                               const int* __restrict__ target,
                               const float* __restrict__ centers,
                               const int* __restrict__ head,
                               const int* __restrict__ next,
                               float* __restrict__ partials,
                               float* __restrict__ out /* d_out base */) {
    int b = blockIdx.x;
    int d = threadIdx.x;
    int t = target[b];
    float c = centers[t * FEAT + d];
    float f = features[b * FEAT + d];
    float diff = c - f;

    // ---- loss partial: block-reduce diff^2 -> partials[b] (plain store)
    float sq = diff * diff;
    #pragma unroll
    for (int off = 32; off > 0; off >>= 1) sq += __shfl_down(sq, off, 64);
    __shared__ float red[4];
    int wave = threadIdx.x >> 6;
    int lane = threadIdx.x & 63;
    if (lane == 0) red[wave] = sq;
    __syncthreads();
    if (threadIdx.x == 0) {
        partials[b] = red[0] + red[1] + red[2] + red[3];
    }

    // ---- center update: only the head block of each class writes the row.
    // delta = sum_s (c - f_s)/(n+eps) = (n*c - sum_f)/(n+eps)
    if (head[t] == b) {
        float sumf = f;
        int n = 1;
        for (int s = next[b]; s != -1; s = next[s]) {
            sumf += features[s * FEAT + d];
            n++;
        }
        float nf = (float)n;
        out[1 + t * FEAT + d] = c - (nf * c - sumf) / (nf + EPS_C);
    }
}

__global__ void finalize_kernel(const float* __restrict__ partials,
                                float* __restrict__ out0) {
    float s = 0.0f;
    for (int i = threadIdx.x; i < BATCH; i += 256) s += partials[i];
    #pragma unroll
    for (int off = 32; off > 0; off >>= 1) s += __shfl_down(s, off, 64);
    __shared__ float red[4];
    int wave = threadIdx.x >> 6;
    int lane = threadIdx.x & 63;
    if (lane == 0) red[wave] = s;
    __syncthreads();
    if (threadIdx.x == 0) {
        out0[0] = (red[0] + red[1] + red[2] + red[3]) / (float)(BATCH * FEAT);
    }
}

extern "C" void kernel_launch(void* const* d_in, const int* in_sizes, int n_in,
                              void* d_out, int out_size, void* d_ws, size_t ws_size,
                              hipStream_t stream) {
    const float* features = (const float*)d_in[0];
    const int*   target   = (const int*)d_in[1];
    const float* centers  = (const float*)d_in[2];
    float* out = (float*)d_out;

    // workspace layout
    int*   head     = (int*)d_ws;                                  // 100000 ints
    int*   next     = head + NCLASS;                               // 8192 ints
    float* partials = (float*)(next + BATCH);                      // 8192 floats

    hipMemsetAsync(head, 0xFF, NCLASS * sizeof(int), stream);      // head = -1
    copy_build_kernel<<<COPY_BLOCKS, 256, 0, stream>>>(centers, out, target, head, next);
    scatter_kernel<<<BATCH, FEAT, 0, stream>>>(features, target, centers,
                                               head, next, partials, out);
    finalize_kernel<<<1, 256, 0, stream>>>(partials, out);
}

// Round 5
// 196.432 us; speedup vs baseline: 3.9673x; 1.0520x over previous
//
#include <hip/hip_runtime.h>

#define BATCH   8192
#define FEAT    256
#define NCLASS  100000
#define EPS_C   1e-6f

#define NC_ELEMS (NCLASS * FEAT)          // 25,600,000
#define NVEC (NC_ELEMS / 4)               // 6,400,000 float4s
#define FUSED_BLOCKS (NVEC / 256)         // 25,000 blocks; each covers 4 rows

// Tiny: build per-class linked lists. head memset to -1 beforehand.
__global__ void build_kernel(const int* __restrict__ target,
                             int* __restrict__ head,
                             int* __restrict__ next) {
    int b = blockIdx.x * blockDim.x + threadIdx.x;
    if (b < BATCH) next[b] = atomicExch(&head[target[b]], b);
}

// One wave per center row (4 rows / 256-thread block).
// Untouched row: plain copy. Touched row: walk the class list, compute
// updated row + per-sample loss partials. Output is shifted +1 float
// (d_out[0] = loss slot) via an LDS staging buffer; the one cross-block
// boundary element is recomputed by thread 0. No atomics, no fences.
__global__ void fused_kernel(const float* __restrict__ centers,
                             const float* __restrict__ features,
                             const int* __restrict__ head,
                             const int* __restrict__ next,
                             float* __restrict__ partials,
                             float* __restrict__ out /* d_out base */) {
    __shared__ float lds[1025];           // [0] = boundary elem, [1..1024] = block's rows
    int w = threadIdx.x >> 6;             // wave 0..3
    int l = threadIdx.x & 63;             // lane
    int r = blockIdx.x * 4 + w;           // center row for this wave

    float4 c4 = ((const float4*)(centers + (size_t)r * FEAT))[l];
    float4 n4 = c4;
    int h = head[r];
    if (h != -1) {
        float4 sumf = {0.f, 0.f, 0.f, 0.f};
        int n = 0;
        for (int s = h; s != -1; s = next[s]) {
            float4 f4 = ((const float4*)(features + (size_t)s * FEAT))[l];
            sumf.x += f4.x; sumf.y += f4.y; sumf.z += f4.z; sumf.w += f4.w;
            float dx = c4.x - f4.x, dy = c4.y - f4.y;
            float dz = c4.z - f4.z, dw = c4.w - f4.w;
            float sq = dx*dx + dy*dy + dz*dz + dw*dw;
            #pragma unroll
            for (int off = 32; off > 0; off >>= 1) sq += __shfl_down(sq, off, 64);
            if (l == 0) partials[s] = sq;   // each sample is in exactly one list
            n++;
        }
        float nf = (float)n;
        float inv = 1.0f / (nf + EPS_C);
        // new = c - (n*c - sum_f)/(n+eps)
        n4.x = c4.x - (nf * c4.x - sumf.x) * inv;
        n4.y = c4.y - (nf * c4.y - sumf.y) * inv;
        n4.z = c4.z - (nf * c4.z - sumf.z) * inv;
        n4.w = c4.w - (nf * c4.w - sumf.w) * inv;
    }

    // stage shifted by +1 into LDS
    int base = 1 + w * 256 + 4 * l;
    lds[base + 0] = n4.x; lds[base + 1] = n4.y;
    lds[base + 2] = n4.z; lds[base + 3] = n4.w;

    // boundary element: new_centers[block_base - 1] (last elem of prev row)
    if (threadIdx.x == 0) {
        float val = 0.0f;                 // block 0: out[0] is loss slot (finalize overwrites)
        if (blockIdx.x > 0) {
            int rp = blockIdx.x * 4 - 1;
            float c = centers[(size_t)rp * FEAT + 255];
            val = c;
            int hp = head[rp];
            if (hp != -1) {
                float sf = 0.0f; int n = 0;
                for (int s = hp; s != -1; s = next[s]) {
                    sf += features[(size_t)s * FEAT + 255]; n++;
                }
                float nf = (float)n;
                val = c - (nf * c - sf) / (nf + EPS_C);
            }
        }
        lds[0] = val;
    }
    // tail element: out[NC_ELEMS] = new_centers[NC_ELEMS-1]
    if (blockIdx.x == FUSED_BLOCKS - 1 && threadIdx.x == 255) {
        out[NC_ELEMS] = n4.w;
    }

    __syncthreads();

    int t = threadIdx.x;
    float4 ov;
    ov.x = lds[4*t + 0]; ov.y = lds[4*t + 1];
    ov.z = lds[4*t + 2]; ov.w = lds[4*t + 3];
    ((float4*)out)[(size_t)blockIdx.x * 256 + t] = ov;
}

__global__ void finalize_kernel(const float* __restrict__ partials,
                                float* __restrict__ out0) {
    float s = 0.0f;
    for (int i = threadIdx.x; i < BATCH; i += 256) s += partials[i];
    #pragma unroll
    for (int off = 32; off > 0; off >>= 1) s += __shfl_down(s, off, 64);
    __shared__ float red[4];
    int wave = threadIdx.x >> 6;
    int lane = threadIdx.x & 63;
    if (lane == 0) red[wave] = s;
    __syncthreads();
    if (threadIdx.x == 0) {
        out0[0] = (red[0] + red[1] + red[2] + red[3]) / (float)(BATCH * FEAT);
    }
}

extern "C" void kernel_launch(void* const* d_in, const int* in_sizes, int n_in,
                              void* d_out, int out_size, void* d_ws, size_t ws_size,
                              hipStream_t stream) {
    const float* features = (const float*)d_in[0];
    const int*   target   = (const int*)d_in[1];
    const float* centers  = (const float*)d_in[2];
    float* out = (float*)d_out;

    int*   head     = (int*)d_ws;                                  // 100000 ints
    int*   next     = head + NCLASS;                               // 8192 ints
    float* partials = (float*)(next + BATCH);                      // 8192 floats

    hipMemsetAsync(head, 0xFF, NCLASS * sizeof(int), stream);      // head = -1
    build_kernel<<<(BATCH + 255) / 256, 256, 0, stream>>>(target, head, next);
    fused_kernel<<<FUSED_BLOCKS, 256, 0, stream>>>(centers, features, head, next,
                                                   partials, out);
    finalize_kernel<<<1, 256, 0, stream>>>(partials, out);
}